// Round 12
// baseline (25.232 us; speedup 1.0000x reference)
//
#include <hip/hip_runtime.h>

// BilateralFilter fp32 I/O, 8 images 512x512, 3x3, sigma=0.8.
// v12: sliding-window row strips. Wave = 8-row x 128-col strip, 2 px/lane/row.
// 3-row fp16 window set rotates through registers; each input row loaded ONCE
// per wave (1.25x vertical redundancy vs 3x before). Packed-fp16 compute,
// poly-exp (zero transcendentals), fp32 epilogue. Zero-pad rows handled
// exactly (contribute to Swd/Swc like the reference).

typedef _Float16 h2 __attribute__((ext_vector_type(2)));

constexpr int HH = 512, WW = 512, HW = HH * WW;
constexpr int RS = 8;                 // output rows per wave

__device__ __forceinline__ h2 H2c(float v) { return h2{(_Float16)v, (_Float16)v}; }
__device__ __forceinline__ h2 pkrtz(float a, float b) {
    return __builtin_bit_cast(h2, __builtin_amdgcn_cvt_pkrtz(a, b));
}

// w(s)=e^(-0.78125*s), s=d^2 in [0,1]; deg-4 Taylor at s=0.5 (rel err ~5e-5)
__device__ __forceinline__ h2 wpoly(h2 d) {
    h2 v = d * d + H2c(-0.5f);
    h2 w = H2c(-0.0537742f) + v * H2c(0.0105029f);
    w = H2c(0.206495f) + v * w;
    w = H2c(-0.528620f) + v * w;
    w = H2c(0.676634f) + v * w;
    return w;
}

#define WS0f 0.2724967f
#define WS1f 0.1247577f
#define WS2f 0.0571180f

struct Win { h2 d[3], m[3], x[3], y[3], z[3]; };   // 15 VGPR
struct Raw { float2 dm,dl,dr, mm,ml,mr, xm,xl,xr, ym,yl,yr, zm,zl,zr; };
struct Acc { h2 swd, swc, st, s0, s1, s2; };

__global__ __launch_bounds__(256) void bilateral_v12(
    const float* __restrict__ depth,
    const float* __restrict__ color,
    const float* __restrict__ mask,
    float* __restrict__ out)
{
    const int lane = threadIdx.x & 63;
    const int b    = blockIdx.x;
    // XCD swizzle: 512 blocks, 8 XCDs -> XCD x owns image x (64 blocks).
    const int logical = (b & 7) * 64 + (b >> 3);
    const int wv   = logical * 4 + (int)(threadIdx.x >> 6);
    const int n    = wv >> 8;          // image 0..7 (256 waves each)
    const int rem  = wv & 255;
    const int rs   = rem >> 2;         // row strip 0..63
    const int cs   = rem & 3;          // col strip 0..3
    const int r0   = rs * RS;
    const int w0   = cs * 128 + lane * 2;

    const float* dptr = depth + (size_t)n * HW;
    const float* mptr = mask  + (size_t)n * HW;
    const float* xptr = color + (size_t)n * 3 * HW;
    const float* yptr = xptr + HW;
    const float* zptr = xptr + 2 * HW;
    float* outn = out + (size_t)n * 3 * HW;

    const bool hasL = (w0 > 0);
    const bool hasR = (w0 < WW - 2);
    const int  colL = hasL ? w0 - 2 : w0;   // aligned float2, clamped
    const int  colR = hasR ? w0 + 2 : w0;

#define LOADR(R_, row) do {                                                  \
    const int _o = (row) * WW;                                               \
    R_.dm = *reinterpret_cast<const float2*>(dptr + _o + w0);                \
    R_.dl = *reinterpret_cast<const float2*>(dptr + _o + colL);              \
    R_.dr = *reinterpret_cast<const float2*>(dptr + _o + colR);              \
    R_.mm = *reinterpret_cast<const float2*>(mptr + _o + w0);                \
    R_.ml = *reinterpret_cast<const float2*>(mptr + _o + colL);              \
    R_.mr = *reinterpret_cast<const float2*>(mptr + _o + colR);              \
    R_.xm = *reinterpret_cast<const float2*>(xptr + _o + w0);                \
    R_.xl = *reinterpret_cast<const float2*>(xptr + _o + colL);              \
    R_.xr = *reinterpret_cast<const float2*>(xptr + _o + colR);              \
    R_.ym = *reinterpret_cast<const float2*>(yptr + _o + w0);                \
    R_.yl = *reinterpret_cast<const float2*>(yptr + _o + colL);              \
    R_.yr = *reinterpret_cast<const float2*>(yptr + _o + colR);              \
    R_.zm = *reinterpret_cast<const float2*>(zptr + _o + w0);                \
    R_.zl = *reinterpret_cast<const float2*>(zptr + _o + colL);              \
    R_.zr = *reinterpret_cast<const float2*>(zptr + _o + colR);              \
} while (0)

// packs: 0=(w0-1,w0) 1=(w0,w0+1) 2=(w0+1,w0+2)
#define CVT1(dst, Rm, Rl, Rr) do {                                           \
    dst[0] = pkrtz(hasL ? (Rl).y : 0.0f, (Rm).x);                            \
    dst[1] = pkrtz((Rm).x, (Rm).y);                                          \
    dst[2] = pkrtz((Rm).y, hasR ? (Rr).x : 0.0f);                            \
} while (0)

#define CVTW(W_, R_) do {                                                    \
    CVT1(W_.d, R_.dm, R_.dl, R_.dr);                                         \
    CVT1(W_.m, R_.mm, R_.ml, R_.mr);                                         \
    CVT1(W_.x, R_.xm, R_.xl, R_.xr);                                         \
    CVT1(W_.y, R_.ym, R_.yl, R_.yr);                                         \
    CVT1(W_.z, R_.zm, R_.zl, R_.zr);                                         \
} while (0)

#define ZEROW(W_) do {                                                       \
    _Pragma("unroll") for (int _j = 0; _j < 3; ++_j) {                       \
        W_.d[_j] = h2{0,0}; W_.m[_j] = h2{0,0}; W_.x[_j] = h2{0,0};          \
        W_.y[_j] = h2{0,0}; W_.z[_j] = h2{0,0};                              \
    }                                                                        \
} while (0)

#define TAP(S_, pi, WSC, A_) do {                                            \
    const h2 _wd = wpoly(S_.d[pi] - cD);                                     \
    const h2 _w0 = wpoly(S_.x[pi] - cX);                                     \
    const h2 _w1 = wpoly(S_.y[pi] - cY);                                     \
    const h2 _w2 = wpoly(S_.z[pi] - cZ);                                     \
    const h2 _wc = _w0 + _w1 + _w2;                                          \
    const h2 _t  = (_wd * _wc) * (H2c(WSC) * S_.m[pi]);                      \
    A_.swd += _wd; A_.swc += _wc; A_.st += _t;                               \
    A_.s0 += _t * S_.x[pi]; A_.s1 += _t * S_.y[pi]; A_.s2 += _t * S_.z[pi];  \
} while (0)

// One step: prefetch row r0+i+2 into WP's slot, compute output row r0+i
// from (WP=row r-1, WC=row r, WN=row r+1), store, rotate.
#define STEP(i, WP, WC, WN) do {                                             \
    Raw raw;                                                                 \
    const int  ldr = r0 + (i) + 2;                                           \
    const bool ldv = (ldr < HH);          /* wave-uniform */                 \
    if (ldv) LOADR(raw, ldr);                                                \
    const h2 cD = WC.d[1], cX = WC.x[1], cY = WC.y[1], cZ = WC.z[1];         \
    Acc A{};                                                                 \
    TAP(WP, 0, WS2f, A); TAP(WP, 1, WS1f, A); TAP(WP, 2, WS2f, A);           \
    TAP(WC, 0, WS1f, A); TAP(WC, 1, WS0f, A); TAP(WC, 2, WS1f, A);           \
    TAP(WN, 0, WS2f, A); TAP(WN, 1, WS1f, A); TAP(WN, 2, WS2f, A);           \
    const float g0  = (float)A.st[0]                                         \
                    + 9e-7f * (float)A.swd[0] * (float)A.swc[0];             \
    const float g1  = (float)A.st[1]                                         \
                    + 9e-7f * (float)A.swd[1] * (float)A.swc[1];             \
    const float iv0 = __builtin_amdgcn_rcpf(g0);                             \
    const float iv1 = __builtin_amdgcn_rcpf(g1);                             \
    float* _po = outn + (r0 + (i)) * WW + w0;                                \
    *reinterpret_cast<float2*>(_po)                                          \
        = make_float2((float)A.s0[0] * iv0, (float)A.s0[1] * iv1);           \
    *reinterpret_cast<float2*>(_po + HW)                                     \
        = make_float2((float)A.s1[0] * iv0, (float)A.s1[1] * iv1);           \
    *reinterpret_cast<float2*>(_po + 2 * HW)                                 \
        = make_float2((float)A.s2[0] * iv0, (float)A.s2[1] * iv1);           \
    if (ldv) CVTW(WP, raw); else ZEROW(WP);                                  \
} while (0)

    Win W0, W1, W2;
    {   // Prologue: rows r0-1 (or zero), r0, r0+1. Issue all loads first.
        Raw ra, rb, rc;
        const bool v0 = (r0 > 0);
        if (v0) LOADR(ra, r0 - 1);
        LOADR(rb, r0);
        LOADR(rc, r0 + 1);
        if (v0) CVTW(W0, ra); else ZEROW(W0);
        CVTW(W1, rb);
        CVTW(W2, rc);
    }

    STEP(0, W0, W1, W2);
    STEP(1, W1, W2, W0);
    STEP(2, W2, W0, W1);
    STEP(3, W0, W1, W2);
    STEP(4, W1, W2, W0);
    STEP(5, W2, W0, W1);
    STEP(6, W0, W1, W2);
    STEP(7, W1, W2, W0);
}

extern "C" void kernel_launch(void* const* d_in, const int* in_sizes, int n_in,
                              void* d_out, int out_size, void* d_ws, size_t ws_size,
                              hipStream_t stream) {
    const float* depth = (const float*)d_in[0];
    const float* color = (const float*)d_in[1];
    const float* mask  = (const float*)d_in[2];
    float* out = (float*)d_out;

    // 8 images * 64 row-strips * 4 col-strips = 2048 waves; 4 waves/block
    bilateral_v12<<<512, 256, 0, stream>>>(depth, color, mask, out);
}